// Round 5
// baseline (74.535 us; speedup 1.0000x reference)
//
#include <hip/hip_runtime.h>
#include <hip/hip_bf16.h>
#include <stdint.h>

// RoICrop: bilinear sampling with border clamp.
// input1: [R=128, C=512, H=37, W=37] f32
// input2: [R=128, 14, 14, 2] f32 in [-1,1], (y, x)
// out:    [R, C, 14, 14] f32
//
// Barrier-free per-wave design (round 4) + 16B-ALIGNED DMA:
// plane byte base = idx*5476 == 4*(idx&3) (mod 16), so 3/4 of waves issued
// misaligned dwordx4 global_load_lds. Now each wave stages from the aligned
// floor (343 x 16B slots = 5488 B >= off+5476) and the gather base shifts by
// (idx&3) floats. Tail slots may hold garbage (never read); per-lane clamp
// keeps the last plane's reads inside the buffer.

#define RR 128
#define CC 512
#define HH 37
#define WW 37
#define NP 196                    // 14*14
#define PLANE 1369                // floats; 5476 B
#define PLANE_PAD 1376            // 5504 B LDS region per wave
#define NBLK (RR * (CC / 4))      // 16384
#define TOTAL_BYTES (358875136ULL) // 128*512*1369*4

typedef __attribute__((address_space(1))) const void gconst_void;
typedef __attribute__((address_space(3))) void lds_void;

__global__ __launch_bounds__(256) void roicrop_kernel(
    const float* __restrict__ feat,
    const float* __restrict__ grid,
    float* __restrict__ out)
{
    __shared__ float s_plane[4][PLANE_PAD];   // 22016 B

    const int blk = blockIdx.x;
    const int r   = blk >> 7;                 // / (CC/4)=128
    const int cb  = blk & 127;
    const int wave = threadIdx.x >> 6;
    const int lane = threadIdx.x & 63;
    const int c   = cb * 4 + wave;            // this wave's channel

    const size_t idx = (size_t)r * CC + c;
    const size_t b   = idx * (size_t)(PLANE * 4);  // plane byte offset
    const int    sh  = (int)(idx & 3);             // float shift; byte off = 4*sh
    const char*  srcA   = (const char*)feat + (b - 4 * (size_t)sh);  // 16B aligned
    const char*  srcEnd = (const char*)feat + (TOTAL_BYTES - 16);
    char* dstb = (char*)&s_plane[wave][0];

    // ---- 1) fire this wave's aligned plane DMA (6 instrs: 5 full + 23-lane tail) ----
    #pragma unroll
    for (int ch = 0; ch < 5; ++ch) {
        __builtin_amdgcn_global_load_lds(
            (gconst_void*)(srcA + ch * 1024 + lane * 16),
            (lds_void*)(dstb + ch * 1024 + lane * 16), 16, 0, 0);
    }
    if (lane < 23) {   // slots 320..342 -> bytes 5120..5487
        const char* sa = srcA + 5120 + lane * 16;
        if (sa > srcEnd) sa = srcEnd;   // only final plane's garbage slots clamp
        __builtin_amdgcn_global_load_lds(
            (gconst_void*)sa,
            (lds_void*)(dstb + 5120 + lane * 16), 16, 0, 0);
    }

    // ---- 2) grid math -> registers (overlaps DMA) ----
    const float2* gp = reinterpret_cast<const float2*>(grid) + (size_t)r * NP;
    float wy[4], wx[4];
    uint32_t pa[4], pb[4];
    #pragma unroll
    for (int t = 0; t < 4; ++t) {
        const int p = lane + 64 * t;
        wy[t] = 0.f; wx[t] = 0.f; pa[t] = 0; pb[t] = 0;
        if (p < NP) {
            float2 g2 = gp[p];
            float y = (g2.x + 1.0f) * 18.0f;   // (H-1)/2
            float x = (g2.y + 1.0f) * 18.0f;
            float y0f = floorf(y), x0f = floorf(x);
            wy[t] = y - y0f; wx[t] = x - x0f;
            int y0 = (int)y0f, x0 = (int)x0f;
            int y0i = min(max(y0,     0), HH - 1);
            int y1i = min(max(y0 + 1, 0), HH - 1);
            int x0i = min(max(x0,     0), WW - 1);
            int x1i = min(max(x0 + 1, 0), WW - 1);
            pa[t] = (uint32_t)(y0i * WW + x0i) | ((uint32_t)(y0i * WW + x1i) << 16);
            pb[t] = (uint32_t)(y1i * WW + x0i) | ((uint32_t)(y1i * WW + x1i) << 16);
        }
    }

    // ---- 3) wait for OWN plane only (per-wave vmcnt; no barrier) ----
    asm volatile("s_waitcnt vmcnt(0)" ::: "memory");
    __builtin_amdgcn_sched_barrier(0);

    // ---- 4) gather + lerp + non-temporal store ----
    const float* pl = &s_plane[wave][sh];     // shifted base
    float* dstp = out + idx * NP;
    #pragma unroll
    for (int t = 0; t < 4; ++t) {
        const int p = lane + 64 * t;
        if (p < NP) {
            float v00 = pl[pa[t] & 0xffffu];
            float v01 = pl[pa[t] >> 16];
            float v10 = pl[pb[t] & 0xffffu];
            float v11 = pl[pb[t] >> 16];
            float top = v00 + (v01 - v00) * wx[t];
            float bot = v10 + (v11 - v10) * wx[t];
            __builtin_nontemporal_store(top + (bot - top) * wy[t], dstp + p);
        }
    }
}

extern "C" void kernel_launch(void* const* d_in, const int* in_sizes, int n_in,
                              void* d_out, int out_size, void* d_ws, size_t ws_size,
                              hipStream_t stream) {
    const float* feat = (const float*)d_in[0];
    const float* grid = (const float*)d_in[1];
    float* out = (float*)d_out;
    roicrop_kernel<<<dim3(NBLK), dim3(256), 0, stream>>>(feat, grid, out);
}

// Round 6
// 68.366 us; speedup vs baseline: 1.0902x; 1.0902x over previous
//
#include <hip/hip_runtime.h>
#include <hip/hip_bf16.h>
#include <stdint.h>

// RoICrop: bilinear sampling with border clamp.
// input1: [R=128, C=512, H=37, W=37] f32
// input2: [R=128, 14, 14, 2] f32 in [-1,1], (y, x)
// out:    [R, C, 14, 14] f32
//
// Barrier-free per-wave design: wave w of each block owns one channel plane
// end-to-end (stage 5.5 KB to LDS via 16B-aligned global_load_lds with NT
// cache policy, grid math in registers under the DMA, per-wave vmcnt(0),
// gather, NT store). Round-6 deltas:
//  - aux=2 (nt) on staging DMA: feature stream is read-once, keep it out of L2
//  - single-base gather: o = ybase*37+xbase with clamp-adjusted weights
//    (ybase=clamp(floor(y),0,35), wy'=clamp(y,0,36)-ybase); corners are
//    pl[o], pl[o+1], pl[o+37], pl[o+38] -> two ds_read2_b32 per point.

#define RR 128
#define CC 512
#define HH 37
#define WW 37
#define NP 196                    // 14*14
#define PLANE 1369                // floats; 5476 B
#define PLANE_PAD 1376            // 5504 B LDS region per wave
#define NBLK (RR * (CC / 4))      // 16384
#define TOTAL_BYTES (358875136ULL) // 128*512*1369*4

typedef __attribute__((address_space(1))) const void gconst_void;
typedef __attribute__((address_space(3))) void lds_void;

__global__ __launch_bounds__(256) void roicrop_kernel(
    const float* __restrict__ feat,
    const float* __restrict__ grid,
    float* __restrict__ out)
{
    __shared__ float s_plane[4][PLANE_PAD];   // 22016 B

    const int blk = blockIdx.x;
    const int r   = blk >> 7;                 // / (CC/4)=128
    const int cb  = blk & 127;
    const int wave = threadIdx.x >> 6;
    const int lane = threadIdx.x & 63;
    const int c   = cb * 4 + wave;            // this wave's channel

    const size_t idx = (size_t)r * CC + c;
    const size_t b   = idx * (size_t)(PLANE * 4);  // plane byte offset
    const int    sh  = (int)(idx & 3);             // float shift; byte off = 4*sh
    const char*  srcA   = (const char*)feat + (b - 4 * (size_t)sh);  // 16B aligned
    const char*  srcEnd = (const char*)feat + (TOTAL_BYTES - 16);
    char* dstb = (char*)&s_plane[wave][0];

    // ---- 1) fire this wave's aligned plane DMA (nt: read-once stream) ----
    #pragma unroll
    for (int ch = 0; ch < 5; ++ch) {
        __builtin_amdgcn_global_load_lds(
            (gconst_void*)(srcA + ch * 1024 + lane * 16),
            (lds_void*)(dstb + ch * 1024 + lane * 16), 16, 0, 2 /*nt*/);
    }
    if (lane < 23) {   // slots 320..342 -> bytes 5120..5487
        const char* sa = srcA + 5120 + lane * 16;
        if (sa > srcEnd) sa = srcEnd;   // only final plane's garbage slots clamp
        __builtin_amdgcn_global_load_lds(
            (gconst_void*)sa,
            (lds_void*)(dstb + 5120 + lane * 16), 16, 0, 2 /*nt*/);
    }

    // ---- 2) grid math -> registers (overlaps DMA) ----
    // ybase = clamp(floor(y),0,35), wy' = clamp(y,0,36) - ybase  (border-exact)
    const float2* gp = reinterpret_cast<const float2*>(grid) + (size_t)r * NP;
    float wy[4], wx[4];
    int   ob[4];
    #pragma unroll
    for (int t = 0; t < 4; ++t) {
        const int p = lane + 64 * t;
        wy[t] = 0.f; wx[t] = 0.f; ob[t] = 0;
        if (p < NP) {
            float2 g2 = gp[p];
            float y = (g2.x + 1.0f) * 18.0f;   // (H-1)/2
            float x = (g2.y + 1.0f) * 18.0f;
            int yb = min(max((int)floorf(y), 0), HH - 2);
            int xb = min(max((int)floorf(x), 0), WW - 2);
            wy[t] = fminf(fmaxf(y, 0.f), 36.f) - (float)yb;
            wx[t] = fminf(fmaxf(x, 0.f), 36.f) - (float)xb;
            ob[t] = yb * WW + xb;
        }
    }

    // ---- 3) wait for OWN plane only (per-wave vmcnt; no barrier) ----
    asm volatile("s_waitcnt vmcnt(0)" ::: "memory");
    __builtin_amdgcn_sched_barrier(0);

    // ---- 4) gather (ds_read2 pairs) + lerp + non-temporal store ----
    const float* pl = &s_plane[wave][sh];     // shifted base
    float* dstp = out + idx * NP;
    #pragma unroll
    for (int t = 0; t < 4; ++t) {
        const int p = lane + 64 * t;
        if (p < NP) {
            const float* q = pl + ob[t];
            float v00 = q[0];
            float v01 = q[1];
            float v10 = q[WW];
            float v11 = q[WW + 1];
            float top = v00 + (v01 - v00) * wx[t];
            float bot = v10 + (v11 - v10) * wx[t];
            __builtin_nontemporal_store(top + (bot - top) * wy[t], dstp + p);
        }
    }
}

extern "C" void kernel_launch(void* const* d_in, const int* in_sizes, int n_in,
                              void* d_out, int out_size, void* d_ws, size_t ws_size,
                              hipStream_t stream) {
    const float* feat = (const float*)d_in[0];
    const float* grid = (const float*)d_in[1];
    float* out = (float*)d_out;
    roicrop_kernel<<<dim3(NBLK), dim3(256), 0, stream>>>(feat, grid, out);
}